// Round 1
// baseline (3481.104 us; speedup 1.0000x reference)
//
#include <hip/hip_runtime.h>
#include <math.h>

#define V 32000
#define CHI 64
#define PD 64
#define NB 8
#define T 512
#define LN_EPS 1e-5f

typedef __attribute__((ext_vector_type(8))) short short8;
typedef __attribute__((ext_vector_type(4))) float f32x4;

__device__ __forceinline__ unsigned short f2b(float x) {
    unsigned int u = __float_as_uint(x);
    unsigned int r = (u + 0x7fffu + ((u >> 16) & 1u)) >> 16;
    return (unsigned short)r;
}
__device__ __forceinline__ float b2f(unsigned short h) {
    return __uint_as_float(((unsigned int)h) << 16);
}

// ---------------- K1: ml/mr modulation (pos MLP) ----------------
__global__ void k_mod(const float* __restrict__ pos, const float* __restrict__ W1,
                      const float* __restrict__ b1, const float* __restrict__ W2,
                      const float* __restrict__ b2, float* __restrict__ ml,
                      float* __restrict__ mr, unsigned short* __restrict__ mrb) {
    int t = blockIdx.x, tid = threadIdx.x;
    __shared__ float pos_s[64];
    __shared__ float hm_s[128];
    if (tid < 64) pos_s[tid] = pos[t * 64 + tid];
    __syncthreads();
    float acc = b1[tid];
#pragma unroll
    for (int p = 0; p < 64; p++) acc += pos_s[p] * W1[p * 128 + tid];
    float g = acc * 0.5f * (1.0f + erff(acc * 0.70710678118654752f)); // exact GELU
    hm_s[tid] = g;
    __syncthreads();
    float acc2 = b2[tid];
#pragma unroll
    for (int k = 0; k < 128; k++) acc2 += hm_s[k] * W2[k * 128 + tid];
    float val = 1.0f + 0.5f * tanhf(acc2);
    if (tid < 64) ml[t * 64 + tid] = val;
    else { int c = tid - 64; mr[t * 64 + c] = val; mrb[t * 72 + c] = f2b(val); }
    if (tid < 8) mrb[t * 72 + 64 + tid] = 0;  // pad so uint4 copies read defined data
}

// ---------------- K2: sequential recurrence, one block per batch elem ----------------
// h_mod[t][b][i] (bf16) is the only output consumed later.
__global__ void __launch_bounds__(64) k_scan(
    const int* __restrict__ ids, const float* __restrict__ core,
    const float* __restrict__ h0, const float* __restrict__ ml,
    const float* __restrict__ mr, const float* __restrict__ gam,
    const float* __restrict__ bet, unsigned short* __restrict__ hmod) {
    const int b = blockIdx.x, j = threadIdx.x;
    __shared__ float hm_s[64];
    float h = h0[j];
    const float gj = gam[j], bj = bet[j];
    float bufA[64], bufB[64];
    {
        int x0 = ids[b * T];
#pragma unroll
        for (int i = 0; i < 64; i++) bufA[i] = core[(size_t)i * V * 64 + (size_t)x0 * 64 + j];
    }
#define SCAN_BODY(TT, USE, PF, TPF)                                              \
    {                                                                            \
        int tp = (TPF); if (tp > T - 1) tp = T - 1;                              \
        int xp = ids[b * T + tp];                                                \
        _Pragma("unroll")                                                        \
        for (int i = 0; i < 64; i++) PF[i] = core[(size_t)i * V * 64 + (size_t)xp * 64 + j]; \
        float hmj = h * ml[(TT) * 64 + j];                                       \
        hmod[((TT) * 8 + b) * 64 + j] = f2b(hmj);                                \
        __syncthreads();                                                         \
        hm_s[j] = hmj;                                                           \
        __syncthreads();                                                         \
        float s = 0.f;                                                           \
        _Pragma("unroll")                                                        \
        for (int i = 0; i < 64; i++) s += hm_s[i] * USE[i];                      \
        float y = s * mr[(TT) * 64 + j];                                         \
        float sum = y, sq = y * y;                                               \
        _Pragma("unroll")                                                        \
        for (int m = 1; m < 64; m <<= 1) { sum += __shfl_xor(sum, m, 64); sq += __shfl_xor(sq, m, 64); } \
        float mu = sum * (1.f / 64.f);                                           \
        float var = sq * (1.f / 64.f) - mu * mu;                                 \
        h = (y - mu) * rsqrtf(var + LN_EPS) * gj + bj;                           \
    }
    for (int t = 0; t < T; t += 2) {
        SCAN_BODY(t, bufA, bufB, t + 1)
        SCAN_BODY(t + 1, bufB, bufA, t + 2)
    }
#undef SCAN_BODY
}

// ---------------- K3: fused logits + online logsumexp ----------------
// Block owns 32 v's (4 tiles of 8). Per v-tile: stage core->LDS bf16 (read once
// device-wide), loop 16 chunks of 32 t:
//   stage A (MFMA): r3[t][v][i] = sum_j mr[t][j]*core[i][v][j]
//   stage B (MFMA): logits[b][v] per t; lane butterfly -> online (m,s) in LDS.
__global__ void __launch_bounds__(512) k_logits(
    const float* __restrict__ core, const unsigned short* __restrict__ mrb,
    const unsigned short* __restrict__ hmod, const float* __restrict__ obias,
    const int* __restrict__ tgt, float* __restrict__ ws_m,
    float* __restrict__ ws_s, float* __restrict__ ws_tgt) {
    __shared__ __attribute__((aligned(16))) unsigned short Cb[8 * 64 * 64]; // swizzled
    __shared__ __attribute__((aligned(16))) unsigned short mrc[32 * 72];
    __shared__ __attribute__((aligned(16))) unsigned short hmc[32 * 8 * 72];
    __shared__ __attribute__((aligned(16))) unsigned short r3s[32 * 8 * 72];
    __shared__ unsigned int lsePS[16 * 32 * 8]; // packed bf16: m<<16 | s
    __shared__ int tgl[32 * 8];

    const int tid = threadIdx.x;
    const int lane = tid & 63;
    const int w = tid >> 6;
    const int q = lane >> 4;
    const int l15 = lane & 15;
    const int bx = blockIdx.x;

    for (int vt = 0; vt < 4; vt++) {
        const int vbase = bx * 32 + vt * 8;
        __syncthreads();
        // stage core tile -> bf16 LDS, XOR-swizzled on j (bits 4-5 by i&3)
        for (int e = 0; e < 16; e++) {
            int u = e * 512 + tid;
            int i = u >> 7, r = u & 127, v = r >> 4, j4 = r & 15;
            const f32x4 c4 = *(reinterpret_cast<const f32x4*>(core) +
                               ((size_t)i * V + (vbase + v)) * 16 + j4);
            int js = (j4 * 4) ^ ((i & 3) << 4);
            unsigned int p0 = ((unsigned int)f2b(c4.y) << 16) | f2b(c4.x);
            unsigned int p1 = ((unsigned int)f2b(c4.w) << 16) | f2b(c4.z);
            unsigned int* dp = reinterpret_cast<unsigned int*>(&Cb[(v * 64 + i) * 64 + js]);
            dp[0] = p0; dp[1] = p1;
        }
        const float bias_v = obias[vbase + (l15 & 7)];
        __syncthreads();

        for (int ch = 0; ch < 16; ch++) {
            // ---- stage hmc / mrc / targets
            for (int e = 0; e < 4; e++) {
                int u = e * 512 + tid;
                int row = u >> 3, seg = u & 7;
                uint4 d = *reinterpret_cast<const uint4*>(
                    hmod + ((size_t)ch * 256 + row) * 64 + seg * 8);
                *reinterpret_cast<uint4*>(&hmc[row * 72 + seg * 8]) = d;
            }
            if (tid < 288) {
                int row = tid / 9, seg = tid % 9;
                *reinterpret_cast<uint4*>(&mrc[row * 72 + seg * 8]) =
                    *reinterpret_cast<const uint4*>(mrb + (ch * 32 + row) * 72 + seg * 8);
            }
            if (tid < 256) tgl[tid] = tgt[(tid & 7) * T + ch * 32 + (tid >> 3)];
            __syncthreads();

            // ---- stage A: wave -> (t-tile = w&1, 2 v's = (w>>1)*2)
            {
                const int att = w & 1;
                const int v0 = (w >> 1) * 2;
                short8 a0 = *reinterpret_cast<const short8*>(&mrc[(att * 16 + l15) * 72 + q * 8]);
                short8 a1 = *reinterpret_cast<const short8*>(&mrc[(att * 16 + l15) * 72 + 32 + q * 8]);
                for (int vv = 0; vv < 2; vv++) {
                    const int v = v0 + vv;
#pragma unroll
                    for (int it = 0; it < 4; it++) {
                        const int i = it * 16 + l15;
                        const int m4 = (i & 3) << 4;
                        short8 bf0 = *reinterpret_cast<const short8*>(&Cb[(v * 64 + i) * 64 + ((q * 8) ^ m4)]);
                        short8 bf1 = *reinterpret_cast<const short8*>(&Cb[(v * 64 + i) * 64 + ((32 + q * 8) ^ m4)]);
                        f32x4 acc = {0.f, 0.f, 0.f, 0.f};
                        acc = __builtin_amdgcn_mfma_f32_16x16x32_bf16(a0, bf0, acc, 0, 0, 0);
                        acc = __builtin_amdgcn_mfma_f32_16x16x32_bf16(a1, bf1, acc, 0, 0, 0);
#pragma unroll
                        for (int r = 0; r < 4; r++) {
                            int trow = att * 16 + q * 4 + r;
                            r3s[(trow * 8 + v) * 72 + it * 16 + l15] = f2b(acc[r]);
                        }
                    }
                }
            }
            __syncthreads();

            // ---- stage B + online lse: wave -> 4 t's
            {
                const int bb = l15 & 7;
#pragma unroll
                for (int e = 0; e < 4; e++) {
                    const int tl = w * 4 + e;
                    short8 ha0 = *reinterpret_cast<const short8*>(&hmc[(tl * 8 + bb) * 72 + q * 8]);
                    short8 ha1 = *reinterpret_cast<const short8*>(&hmc[(tl * 8 + bb) * 72 + 32 + q * 8]);
                    short8 rb0 = *reinterpret_cast<const short8*>(&r3s[(tl * 8 + bb) * 72 + q * 8]);
                    short8 rb1 = *reinterpret_cast<const short8*>(&r3s[(tl * 8 + bb) * 72 + 32 + q * 8]);
                    f32x4 acc = {0.f, 0.f, 0.f, 0.f};
                    acc = __builtin_amdgcn_mfma_f32_16x16x32_bf16(ha0, rb0, acc, 0, 0, 0);
                    acc = __builtin_amdgcn_mfma_f32_16x16x32_bf16(ha1, rb1, acc, 0, 0, 0);
                    float vals[4], mx[4], sm[4];
#pragma unroll
                    for (int r = 0; r < 4; r++) vals[r] = acc[r] + bias_v;
#pragma unroll
                    for (int r = 0; r < 4; r++) {
                        float m = vals[r];
                        m = fmaxf(m, __shfl_xor(m, 1, 64));
                        m = fmaxf(m, __shfl_xor(m, 2, 64));
                        m = fmaxf(m, __shfl_xor(m, 4, 64));
                        float mq = b2f(f2b(m));  // quantize so stored (m,s) stay consistent
                        float e1 = __expf(vals[r] - mq);
                        e1 += __shfl_xor(e1, 1, 64);
                        e1 += __shfl_xor(e1, 2, 64);
                        e1 += __shfl_xor(e1, 4, 64);
                        mx[r] = mq; sm[r] = e1;
                    }
                    const bool valid = (q < 2) && (l15 < 8);
                    if (valid) {
                        const int tg = ch * 32 + tl;
#pragma unroll
                        for (int r = 0; r < 4; r++) {
                            int b = q * 4 + r;
                            if (tgl[tl * 8 + b] == vbase + l15) ws_tgt[b * T + tg] = vals[r];
                        }
                        if (l15 == 0) {
#pragma unroll
                            for (int r = 0; r < 4; r++) {
                                int idx = (ch * 32 + tl) * 8 + q * 4 + r;
                                if (vt == 0) {
                                    lsePS[idx] = ((unsigned int)f2b(mx[r]) << 16) | f2b(sm[r]);
                                } else {
                                    unsigned int pp = lsePS[idx];
                                    float om = b2f((unsigned short)(pp >> 16));
                                    float os = b2f((unsigned short)(pp & 0xffff));
                                    float m2 = fmaxf(om, mx[r]);
                                    float s2 = os * __expf(om - m2) + sm[r] * __expf(mx[r] - m2);
                                    lsePS[idx] = ((unsigned int)f2b(m2) << 16) | f2b(s2);
                                }
                            }
                        }
                    }
                }
            }
            __syncthreads();
        }
    }

    __syncthreads();
    for (int e = 0; e < 8; e++) {
        int p = e * 512 + tid;         // b*512 + t
        unsigned int pp = lsePS[(p & 511) * 8 + (p >> 9)];
        ws_m[(size_t)bx * 4096 + p] = b2f((unsigned short)(pp >> 16));
        ws_s[(size_t)bx * 4096 + p] = b2f((unsigned short)(pp & 0xffff));
    }
}

// ---------------- reduces ----------------
__global__ void k_red1(const float* __restrict__ ws_m, const float* __restrict__ ws_s,
                       float* __restrict__ o_m, float* __restrict__ o_s) {
    int bt = blockIdx.x * 256 + threadIdx.x;
    int kg = blockIdx.y;
    float m = -1e30f, s = 0.f;
    for (int kk = 0; kk < 100; kk++) {
        int k = kg * 100 + kk;
        float mk = ws_m[(size_t)k * 4096 + bt], sk = ws_s[(size_t)k * 4096 + bt];
        float m2 = fmaxf(m, mk);
        s = s * __expf(m - m2) + sk * __expf(mk - m2);
        m = m2;
    }
    o_m[kg * 4096 + bt] = m; o_s[kg * 4096 + bt] = s;
}

__global__ void k_red2(const float* __restrict__ o_m, const float* __restrict__ o_s,
                       const float* __restrict__ wtgt, float* __restrict__ out) {
    int bt = blockIdx.x * 256 + threadIdx.x;
    float m = -1e30f, s = 0.f;
    for (int kg = 0; kg < 10; kg++) {
        float mk = o_m[kg * 4096 + bt], sk = o_s[kg * 4096 + bt];
        float m2 = fmaxf(m, mk);
        s = s * __expf(m - m2) + sk * __expf(mk - m2);
        m = m2;
    }
    float term = m + logf(s) - wtgt[bt];
    __shared__ float red[256];
    red[threadIdx.x] = term;
    __syncthreads();
    for (int st = 128; st > 0; st >>= 1) {
        if (threadIdx.x < st) red[threadIdx.x] += red[threadIdx.x + st];
        __syncthreads();
    }
    if (threadIdx.x == 0) atomicAdd(out, red[0] * (1.f / 4096.f));
}

extern "C" void kernel_launch(void* const* d_in, const int* in_sizes, int n_in,
                              void* d_out, int out_size, void* d_ws, size_t ws_size,
                              hipStream_t stream) {
    const int*   ids   = (const int*)d_in[0];
    const int*   tgt   = (const int*)d_in[1];
    const float* core  = (const float*)d_in[2];
    const float* h0    = (const float*)d_in[3];
    const float* pos   = (const float*)d_in[4];
    const float* W1    = (const float*)d_in[5];
    const float* b1    = (const float*)d_in[6];
    const float* W2    = (const float*)d_in[7];
    const float* b2    = (const float*)d_in[8];
    const float* obias = (const float*)d_in[9];
    const float* gam   = (const float*)d_in[10];
    const float* bet   = (const float*)d_in[11];

    char* ws = (char*)d_ws;
    float*          ws_ml  = (float*)(ws + 0);
    float*          ws_mr  = (float*)(ws + 131072);
    unsigned short* ws_mrb = (unsigned short*)(ws + 262144);
    unsigned short* ws_hm  = (unsigned short*)(ws + 335872);
    float*          ws_tg  = (float*)(ws + 860160);
    float*          ws_m   = (float*)(ws + 876544);
    float*          ws_s   = (float*)(ws + 17260544);
    float*          o2m    = (float*)(ws + 33644544);
    float*          o2s    = (float*)(ws + 33808384);

    hipMemsetAsync(d_out, 0, sizeof(float), stream);

    k_mod<<<512, 128, 0, stream>>>(pos, W1, b1, W2, b2, ws_ml, ws_mr, ws_mrb);
    k_scan<<<NB, 64, 0, stream>>>(ids, core, h0, ws_ml, ws_mr, gam, bet, ws_hm);
    k_logits<<<1000, 512, 0, stream>>>(core, ws_mrb, ws_hm, obias, tgt,
                                       ws_m, ws_s, ws_tg);
    k_red1<<<dim3(16, 10), 256, 0, stream>>>(ws_m, ws_s, o2m, o2s);
    k_red2<<<16, 256, 0, stream>>>(o2m, o2s, ws_tg, (float*)d_out);
}

// Round 2
// 1905.902 us; speedup vs baseline: 1.8265x; 1.8265x over previous
//
#include <hip/hip_runtime.h>
#include <math.h>

#define V 32000
#define T 512
#define NB 8
#define LN_EPS 1e-5f

typedef __attribute__((ext_vector_type(8))) short short8;
typedef __attribute__((ext_vector_type(4))) float f32x4;

__device__ __forceinline__ unsigned short f2b(float x) {
    unsigned int u = __float_as_uint(x);
    unsigned int r = (u + 0x7fffu + ((u >> 16) & 1u)) >> 16;
    return (unsigned short)r;
}
__device__ __forceinline__ float b2f(unsigned short h) {
    return __uint_as_float(((unsigned int)h) << 16);
}
// pack two floats to bf16 pair (round-half-up): low16=bf16(a), high16=bf16(b)
__device__ __forceinline__ unsigned int pack_rn(float a, float b) {
    unsigned int ua = __float_as_uint(a) + 0x8000u;
    unsigned int ub = __float_as_uint(b) + 0x8000u;
    return __builtin_amdgcn_perm(ub, ua, 0x07060302u);
}

// ---------------- K1: ml/mr modulation (pos MLP) ----------------
__global__ void k_mod(const float* __restrict__ pos, const float* __restrict__ W1,
                      const float* __restrict__ b1, const float* __restrict__ W2,
                      const float* __restrict__ b2, float* __restrict__ ml,
                      float* __restrict__ mr, unsigned short* __restrict__ mrb) {
    int t = blockIdx.x, tid = threadIdx.x;
    __shared__ float pos_s[64];
    __shared__ float hm_s[128];
    if (tid < 64) pos_s[tid] = pos[t * 64 + tid];
    __syncthreads();
    float acc = b1[tid];
#pragma unroll
    for (int p = 0; p < 64; p++) acc += pos_s[p] * W1[p * 128 + tid];
    float g = acc * 0.5f * (1.0f + erff(acc * 0.70710678118654752f)); // exact GELU
    hm_s[tid] = g;
    __syncthreads();
    float acc2 = b2[tid];
#pragma unroll
    for (int k = 0; k < 128; k++) acc2 += hm_s[k] * W2[k * 128 + tid];
    float val = 1.0f + 0.5f * tanhf(acc2);
    if (tid < 64) ml[t * 64 + tid] = val;
    else { int c = tid - 64; mr[t * 64 + c] = val; mrb[t * 64 + c] = f2b(val); }
}

// ---------------- K1b: gather core[:, x_t, :] -> contiguous bf16 pairs ----------------
// g[bt][k], k = i2*64 + j holds (core[2*i2][x][j], core[2*i2+1][x][j]) as bf16 pair.
__global__ void __launch_bounds__(256) k_gather(const int* __restrict__ ids,
                                                const float* __restrict__ core,
                                                unsigned int* __restrict__ g) {
    int bt = blockIdx.x;            // b*512 + t
    int b = bt >> 9, t = bt & 511;
    int x = ids[b * T + t];
    unsigned int* dst = g + (size_t)bt * 2048;
#pragma unroll
    for (int e = 0; e < 8; e++) {
        int k = e * 256 + threadIdx.x;
        int i2 = k >> 6, j = k & 63;
        float a = core[((size_t)(2 * i2) * V + x) * 64 + j];
        float c = core[((size_t)(2 * i2 + 1) * V + x) * 64 + j];
        dst[k] = pack_rn(a, c);
    }
}

// ---------------- K2: sequential recurrence, one block (1 wave) per batch elem ----------------
__global__ void __launch_bounds__(64) k_scan(
    const unsigned int* __restrict__ g, const float* __restrict__ h0,
    const float* __restrict__ ml, const float* __restrict__ mr,
    const float* __restrict__ gam, const float* __restrict__ bet,
    unsigned short* __restrict__ hmod) {
    const int b = blockIdx.x, j = threadIdx.x;
    __shared__ float hm_s[64];
    float h = h0[j];
    const float gj = gam[j], bj = bet[j];
    const unsigned int* gb = g + (size_t)b * (512 * 2048);
    unsigned int B0[32], B1[32], B2[32], B3[32];
#pragma unroll
    for (int i = 0; i < 32; i++) B0[i] = gb[i * 64 + j];
#pragma unroll
    for (int i = 0; i < 32; i++) B1[i] = gb[2048 + i * 64 + j];

#define SCAN_BODY(TT, USE, PF)                                                \
    {                                                                         \
        int tp = (TT) + 2; if (tp > T - 1) tp = T - 1;                        \
        const unsigned int* gp = gb + (size_t)tp * 2048;                      \
        _Pragma("unroll")                                                     \
        for (int i = 0; i < 32; i++) PF[i] = gp[i * 64 + j];                  \
        float hmj = h * ml[(TT) * 64 + j];                                    \
        hmod[((TT) * 8 + b) * 64 + j] = f2b(hmj);                             \
        __syncthreads();                                                      \
        hm_s[j] = hmj;                                                        \
        __syncthreads();                                                      \
        float s0 = 0.f, s1 = 0.f;                                             \
        _Pragma("unroll")                                                     \
        for (int i = 0; i < 32; i++) {                                        \
            unsigned int u = USE[i];                                          \
            s0 += __uint_as_float(u << 16) * hm_s[2 * i];                     \
            s1 += __uint_as_float(u & 0xffff0000u) * hm_s[2 * i + 1];         \
        }                                                                     \
        float y = (s0 + s1) * mr[(TT) * 64 + j];                              \
        float sum = y, sq = y * y;                                            \
        _Pragma("unroll")                                                     \
        for (int m = 1; m < 64; m <<= 1) {                                    \
            sum += __shfl_xor(sum, m, 64);                                    \
            sq  += __shfl_xor(sq, m, 64);                                     \
        }                                                                     \
        float mu = sum * (1.f / 64.f);                                        \
        float var = sq * (1.f / 64.f) - mu * mu;                              \
        h = (y - mu) * rsqrtf(var + LN_EPS) * gj + bj;                        \
    }

    for (int t = 0; t < T; t += 4) {
        SCAN_BODY(t, B0, B2)
        SCAN_BODY(t + 1, B1, B3)
        SCAN_BODY(t + 2, B2, B0)
        SCAN_BODY(t + 3, B3, B1)
    }
#undef SCAN_BODY
}

// ---------------- K3: fused logits + LSE partials ----------------
// Block owns 8 v's (4000 blocks). Wave w keeps core[:, v0+w, :] as bf16 MFMA
// A-fragments in registers (loaded once). Per 32-t chunk:
//   stage A: r[t,v,i] = sum_j core[i,v,j] mr[t,j]   (M=i, N=t) -> LDS b64-packed
//   stage B: logits[v,b] per t (M=v, N=b, K=i); 4 v's in-lane -> 2-shuffle LSE,
//   per-(b,t) partial (m,s) packed bf16 straight to global.
__global__ void __launch_bounds__(512, 4) k_logits(
    const float* __restrict__ core, const unsigned short* __restrict__ mrb,
    const unsigned short* __restrict__ hmod, const float* __restrict__ obias,
    const int* __restrict__ tgt, unsigned int* __restrict__ ws_ms,
    float* __restrict__ ws_tgt) {
    __shared__ __attribute__((aligned(16))) unsigned short r3s[8 * 2312];

    const int tid = threadIdx.x;
    const int w = tid >> 6;
    const int lane = tid & 63;
    const int q = lane >> 4;
    const int l15 = lane & 15;
    const int bx = blockIdx.x;
    const int v0 = bx * 8;
    const int myv = v0 + w;

    // persistent core A-fragments: cf[it*2+ks], A[m=i][k=j], i=it*16+l15, j=ks*32+q*8+e
    short8 cf[8];
#pragma unroll
    for (int it = 0; it < 4; it++) {
        const float* p = core + (((size_t)(it * 16 + l15)) * V + myv) * 64;
#pragma unroll
        for (int ks = 0; ks < 2; ks++) {
            f32x4 x0 = *reinterpret_cast<const f32x4*>(p + ks * 32 + q * 8);
            f32x4 x1 = *reinterpret_cast<const f32x4*>(p + ks * 32 + q * 8 + 4);
            union { short8 s; unsigned int u[4]; } pk;
            pk.u[0] = pack_rn(x0.x, x0.y);
            pk.u[1] = pack_rn(x0.z, x0.w);
            pk.u[2] = pack_rn(x1.x, x1.y);
            pk.u[3] = pack_rn(x1.z, x1.w);
            cf[it * 2 + ks] = pk.s;
        }
    }
    float biasv[4];
#pragma unroll
    for (int r = 0; r < 4; r++) biasv[r] = obias[v0 + (q & 1) * 4 + r];

    for (int ch = 0; ch < 16; ch++) {
        const int t0 = ch * 32;
        // ---- stage A: this wave's v, both 16-t tiles
#pragma unroll
        for (int tt = 0; tt < 2; tt++) {
            const int trow = t0 + tt * 16 + l15;
            short8 mf0 = *reinterpret_cast<const short8*>(mrb + trow * 64 + q * 8);
            short8 mf1 = *reinterpret_cast<const short8*>(mrb + trow * 64 + 32 + q * 8);
#pragma unroll
            for (int it = 0; it < 4; it++) {
                f32x4 acc = {0.f, 0.f, 0.f, 0.f};
                acc = __builtin_amdgcn_mfma_f32_16x16x32_bf16(cf[it * 2], mf0, acc, 0, 0, 0);
                acc = __builtin_amdgcn_mfma_f32_16x16x32_bf16(cf[it * 2 + 1], mf1, acc, 0, 0, 0);
                // C[m=i][n=t]: lane col=t-within-tile(l15), rows i=it*16+q*4+r
                uint2 dd;
                dd.x = pack_rn(acc.x, acc.y);
                dd.y = pack_rn(acc.z, acc.w);
                *reinterpret_cast<uint2*>(
                    &r3s[w * 2312 + (tt * 16 + l15) * 72 + it * 16 + q * 4]) = dd;
            }
        }
        __syncthreads();
        // ---- stage B: wave handles 4 t's
        const int bb = l15 & 7;
        const int vp = (l15 & 7) * 2312;
#pragma unroll
        for (int e = 0; e < 4; e++) {
            const int tl = w * 4 + e;
            const int t = t0 + tl;
            short8 ra0 = *reinterpret_cast<const short8*>(&r3s[vp + tl * 72 + q * 8]);
            short8 ra1 = *reinterpret_cast<const short8*>(&r3s[vp + tl * 72 + 32 + q * 8]);
            short8 hb0 = *reinterpret_cast<const short8*>(hmod + ((size_t)t * 8 + bb) * 64 + q * 8);
            short8 hb1 = *reinterpret_cast<const short8*>(hmod + ((size_t)t * 8 + bb) * 64 + 32 + q * 8);
            f32x4 acc = {0.f, 0.f, 0.f, 0.f};
            acc = __builtin_amdgcn_mfma_f32_16x16x32_bf16(ra0, hb0, acc, 0, 0, 0);
            acc = __builtin_amdgcn_mfma_f32_16x16x32_bf16(ra1, hb1, acc, 0, 0, 0);
            float vals[4];
#pragma unroll
            for (int r = 0; r < 4; r++) vals[r] = acc[r] + biasv[r];
            // target logit
            if (q < 2 && l15 < 8) {
                int tg = tgt[bb * T + t];
#pragma unroll
                for (int r = 0; r < 4; r++)
                    if (tg == v0 + q * 4 + r) ws_tgt[l15 * T + t] = vals[r];
            }
            // LSE: 4 v's in-lane, then merge q^1 (covers all 8 v; q2/q3 are dups)
            float m4 = fmaxf(fmaxf(vals[0], vals[1]), fmaxf(vals[2], vals[3]));
            float s4 = __expf(vals[0] - m4) + __expf(vals[1] - m4) +
                       __expf(vals[2] - m4) + __expf(vals[3] - m4);
            float om = __shfl_xor(m4, 16, 64);
            float os = __shfl_xor(s4, 16, 64);
            float mm = fmaxf(m4, om);
            float mq = b2f(f2b(mm));  // quantize max BEFORE forming s (consistency)
            float ss = s4 * __expf(m4 - mq) + os * __expf(om - mq);
            if (q == 0 && l15 < 8) {
                ws_ms[(size_t)bx * 4096 + l15 * T + t] =
                    ((unsigned int)f2b(mq) << 16) | f2b(ss);
            }
        }
        __syncthreads();
    }
}

// ---------------- reduces ----------------
__global__ void k_red1(const unsigned int* __restrict__ ws_ms,
                       float* __restrict__ o_m, float* __restrict__ o_s) {
    int bt = blockIdx.x * 256 + threadIdx.x;
    int kg = blockIdx.y;
    float m = -1e30f, s = 0.f;
    for (int kk = 0; kk < 100; kk++) {
        unsigned int pp = ws_ms[(size_t)(kg * 100 + kk) * 4096 + bt];
        float mk = b2f((unsigned short)(pp >> 16));
        float sk = b2f((unsigned short)(pp & 0xffff));
        float m2 = fmaxf(m, mk);
        s = s * __expf(m - m2) + sk * __expf(mk - m2);
        m = m2;
    }
    o_m[kg * 4096 + bt] = m; o_s[kg * 4096 + bt] = s;
}

__global__ void k_red2(const float* __restrict__ o_m, const float* __restrict__ o_s,
                       const float* __restrict__ wtgt, float* __restrict__ out) {
    int bt = blockIdx.x * 256 + threadIdx.x;
    float m = -1e30f, s = 0.f;
    for (int kg = 0; kg < 40; kg++) {
        float mk = o_m[kg * 4096 + bt], sk = o_s[kg * 4096 + bt];
        float m2 = fmaxf(m, mk);
        s = s * __expf(m - m2) + sk * __expf(mk - m2);
        m = m2;
    }
    float term = m + logf(s) - wtgt[bt];
    __shared__ float red[256];
    red[threadIdx.x] = term;
    __syncthreads();
    for (int st = 128; st > 0; st >>= 1) {
        if (threadIdx.x < st) red[threadIdx.x] += red[threadIdx.x + st];
        __syncthreads();
    }
    if (threadIdx.x == 0) atomicAdd(out, red[0] * (1.f / 4096.f));
}

extern "C" void kernel_launch(void* const* d_in, const int* in_sizes, int n_in,
                              void* d_out, int out_size, void* d_ws, size_t ws_size,
                              hipStream_t stream) {
    const int*   ids   = (const int*)d_in[0];
    const int*   tgt   = (const int*)d_in[1];
    const float* core  = (const float*)d_in[2];
    const float* h0    = (const float*)d_in[3];
    const float* pos   = (const float*)d_in[4];
    const float* W1    = (const float*)d_in[5];
    const float* b1    = (const float*)d_in[6];
    const float* W2    = (const float*)d_in[7];
    const float* b2    = (const float*)d_in[8];
    const float* obias = (const float*)d_in[9];
    const float* gam   = (const float*)d_in[10];
    const float* bet   = (const float*)d_in[11];

    char* ws = (char*)d_ws;
    float*          ws_ml  = (float*)(ws + 0);              // 512*64*4   = 131072
    float*          ws_mr  = (float*)(ws + 131072);         // 131072
    unsigned short* ws_mrb = (unsigned short*)(ws + 262144);// 512*64*2   = 65536
    unsigned short* ws_hm  = (unsigned short*)(ws + 327680);// 512*8*64*2 = 524288
    float*          ws_tg  = (float*)(ws + 851968);         // 4096*4     = 16384
    // g (33.5 MB) aliases the front of ws_ms (65.5 MB): g is dead (scan done)
    // before k_logits writes ws_ms.
    unsigned int*   g      = (unsigned int*)(ws + 868352);
    unsigned int*   ws_ms  = (unsigned int*)(ws + 868352);  // 4000*4096*4 = 65536000
    float*          o2m    = (float*)(ws + 66404352);       // 40*4096*4  = 655360
    float*          o2s    = (float*)(ws + 67059712);       // 655360  (end 67715072)

    hipMemsetAsync(d_out, 0, sizeof(float), stream);

    k_mod<<<512, 128, 0, stream>>>(pos, W1, b1, W2, b2, ws_ml, ws_mr, ws_mrb);
    k_gather<<<4096, 256, 0, stream>>>(ids, core, g);
    k_scan<<<NB, 64, 0, stream>>>(g, h0, ws_ml, ws_mr, gam, bet, ws_hm);
    k_logits<<<4000, 512, 0, stream>>>(core, ws_mrb, ws_hm, obias, tgt, ws_ms, ws_tg);
    k_red1<<<dim3(16, 40), 256, 0, stream>>>(ws_ms, o2m, o2s);
    k_red2<<<16, 256, 0, stream>>>(o2m, o2s, ws_tg, (float*)d_out);
}